// Round 9
// baseline (357.524 us; speedup 1.0000x reference)
//
#include <hip/hip_runtime.h>

// LocalAttention P=7 window attention — split-pipeline bf16 MFMA.
// Round 9: qkvv's fused gather was a runtime-bounded loop -> 37 serialized
// scalar-load latencies per block (~100us of the 177us). Two-phase unrolled
// gather: issue all 37 loads into compile-time-indexed regs, then cvt+store
// to LDS. attn_core / out_proj / prep byte-identical (clean A/B).

#define NWIN 2048
#define OUT0 19267584L

typedef __attribute__((ext_vector_type(8))) short bf16x8;
typedef __attribute__((ext_vector_type(4))) float f32x4;

#define MFMA(a, b, c) __builtin_amdgcn_mfma_f32_16x16x32_bf16(a, b, c, 0, 0, 0)

__device__ __forceinline__ unsigned short f2b(float f) {
  unsigned u = __builtin_bit_cast(unsigned, f);
  return (unsigned short)((u + 0x7FFFu + ((u >> 16) & 1u)) >> 16);
}
__device__ __forceinline__ unsigned pk2(float a, float b) {
  return (unsigned)f2b(a) | ((unsigned)f2b(b) << 16);
}
__device__ __forceinline__ float b2f(unsigned short h) {
  unsigned u = ((unsigned)h) << 16;
  return __builtin_bit_cast(float, u);
}

// ---- workspace layout ----
#define OWS_BYTES  (2048L * 8 * 49 * 32 * 2)   // 51,380,224
#define QK_ROWS    (2048L * 49 + 64)
#define Q_OFF      OWS_BYTES
#define K_OFF      (Q_OFF + QK_ROWS * 256 * 2)
#define V_OFF      (K_OFF + QK_ROWS * 256 * 2)
#define WQKV_OFF   (V_OFF + 2048L * 256 * 64 * 2)
#define WO_OFF     (WQKV_OFF + 768L * 192 * 2)
#define BIAS_OFF   (WO_OFF + 192L * 256 * 2)

// ================= K0: weight cvt + bias table (tiny) =================
__global__ __launch_bounds__(256) void prep(
    const float* __restrict__ mask, const float* __restrict__ Wq,
    const float* __restrict__ Wkv, const float* __restrict__ Wo,
    const float* __restrict__ pos,
    unsigned short* __restrict__ wqkv, unsigned short* __restrict__ wo,
    float* __restrict__ bias)
{
  int gid = blockIdx.x * 256 + threadIdx.x;
  if (gid < 147456)       wqkv[gid] = f2b(gid < 49152 ? Wq[gid] : Wkv[gid - 49152]);
  else if (gid < 196608)  { int i = gid - 147456; wo[i] = f2b(Wo[i]); }
  else if (gid < 199009)  {
    int i = gid - 196608;
    int tq = i / 49, tk = i - tq * 49;
    int r0 = tk / 7 - tq / 7 + 6, r1 = tk % 7 - tq % 7 + 6;
    bias[i] = mask[i] + pos[r0 * 13 + r1];
  }
}

// ================= K1: per-window QKV GEMM, gathers x directly =================
// Block = 1 window, 4 waves. LDS xw [64][200] bf16. Two-phase gather:
// (a) issue 37 unrolled global loads into regs (one latency exposure),
// (b) cvt+ds_write. Then wave w does tiles ti=i*4+w: ti 0..7 Q/K rows
// (A=weights,B=xw), ti 8..11 V (A=xw,B=weights).
__global__ __launch_bounds__(256, 4) void qkvv_gemm(
    const float* __restrict__ x, const unsigned short* __restrict__ wqkv,
    unsigned short* __restrict__ qws, unsigned short* __restrict__ kws,
    unsigned short* __restrict__ vt)
{
  __shared__ __align__(16) unsigned short xw[64 * 200];  // 25600 B
  const int tid = threadIdx.x;
  const int w = tid >> 6, lane = tid & 63;
  const int l15 = lane & 15, lg = lane >> 4;
  const int win = blockIdx.x;
  const int bi = win >> 6, w1 = (win >> 3) & 7, w2 = win & 7;
  const f32x4 zero = {0.f, 0.f, 0.f, 0.f};

  // ---- gather x window -> LDS (two-phase: batch loads, then stores) ----
  {
    const long xbase = (long)bi * 192 * 3136 + (w1 * 7) * 56 + w2 * 7;
    float v[37];
    #pragma unroll
    for (int it = 0; it < 37; ++it) {
      int idx = it * 256 + tid;
      if (idx < 192 * 49) {
        int c = idx / 49, t = idx - c * 49;
        v[it] = x[xbase + c * 3136 + (t / 7) * 56 + (t % 7)];
      }
    }
    #pragma unroll
    for (int it = 0; it < 37; ++it) {
      int idx = it * 256 + tid;
      if (idx < 192 * 49) {
        int c = idx / 49, t = idx - c * 49;
        xw[t * 200 + c] = f2b(v[it]);
      }
    }
    // zero-pad rows 49..63 (360 bf16x8 chunks)
    const bf16x8 z8 = {0, 0, 0, 0, 0, 0, 0, 0};
    #pragma unroll
    for (int it = 0; it < 2; ++it) {
      int idx = it * 256 + tid;
      if (idx < 360) {
        int t = 49 + idx / 24, c8 = (idx - (idx / 24) * 24) * 8;
        *(bf16x8*)(xw + t * 200 + c8) = z8;
      }
    }
  }
  __syncthreads();

  #pragma unroll
  for (int i = 0; i < 3; ++i) {
    const int ti = i * 4 + w;
    const int e_base = ti * 64;
    f32x4 acc[4][4];
    #pragma unroll
    for (int a = 0; a < 4; ++a)
      #pragma unroll
      for (int b = 0; b < 4; ++b) acc[a][b] = zero;

    if (i < 2) {
      // Q/K tile: D[e][t]
      #pragma unroll
      for (int ks = 0; ks < 6; ++ks) {
        const int kc = ks * 32 + lg * 8;
        bf16x8 a[4], b[4];
        #pragma unroll
        for (int mi = 0; mi < 4; ++mi)
          a[mi] = *(const bf16x8*)(wqkv + (e_base + mi * 16 + l15) * 192 + kc);
        #pragma unroll
        for (int ni = 0; ni < 4; ++ni)
          b[ni] = *(const bf16x8*)(xw + (ni * 16 + l15) * 200 + kc);
        #pragma unroll
        for (int mi = 0; mi < 4; ++mi)
          #pragma unroll
          for (int ni = 0; ni < 4; ++ni)
            acc[mi][ni] = MFMA(a[mi], b[ni], acc[mi][ni]);
      }
      #pragma unroll
      for (int ni = 0; ni < 4; ++ni) {
        int tq = ni * 16 + l15;
        if (tq < 49) {
          #pragma unroll
          for (int mi = 0; mi < 4; ++mi) {
            int e0 = e_base + mi * 16 + lg * 4;
            unsigned short* dst = (e0 < 256) ? qws : kws;
            int e = e0 & 255;
            uint2 v = {pk2(acc[mi][ni][0], acc[mi][ni][1]),
                       pk2(acc[mi][ni][2], acc[mi][ni][3])};
            *(uint2*)(dst + ((long)win * 49 + tq) * 256 + e) = v;
          }
        }
      }
    } else {
      // V tile: D[t][e]
      const int ev0 = e_base - 512;
      #pragma unroll
      for (int ks = 0; ks < 6; ++ks) {
        const int kc = ks * 32 + lg * 8;
        bf16x8 a[4], b[4];
        #pragma unroll
        for (int mi = 0; mi < 4; ++mi)
          a[mi] = *(const bf16x8*)(xw + (mi * 16 + l15) * 200 + kc);
        #pragma unroll
        for (int ni = 0; ni < 4; ++ni)
          b[ni] = *(const bf16x8*)(wqkv + (512 + ev0 + ni * 16 + l15) * 192 + kc);
        #pragma unroll
        for (int mi = 0; mi < 4; ++mi)
          #pragma unroll
          for (int ni = 0; ni < 4; ++ni)
            acc[mi][ni] = MFMA(a[mi], b[ni], acc[mi][ni]);
      }
      #pragma unroll
      for (int mi = 0; mi < 4; ++mi) {
        int tl = mi * 16 + lg * 4;
        #pragma unroll
        for (int ni = 0; ni < 4; ++ni) {
          int e = ev0 + ni * 16 + l15;
          uint2 v = {pk2(acc[mi][ni][0], acc[mi][ni][1]),
                     pk2(acc[mi][ni][2], acc[mi][ni][3])};
          *(uint2*)(vt + ((long)win * 256 + e) * 64 + tl) = v;
        }
      }
    }
  }
}

// ================= K2: attention core (1 wave = 1 (win,head)) =================
#define PSTRIDE 6272

__global__ __launch_bounds__(256, 4) void attn_core(
    const unsigned short* __restrict__ qws, const unsigned short* __restrict__ kws,
    const unsigned short* __restrict__ vt, const float* __restrict__ bias,
    float* __restrict__ attn_out, unsigned short* __restrict__ o_ws)
{
  __shared__ __align__(16) char lds[4 * PSTRIDE];
  const int tid = threadIdx.x;
  const int w = tid >> 6, lane = tid & 63;
  const int l15 = lane & 15, lg = lane >> 4;
  const int gw = blockIdx.x * 4 + w;
  const int win = gw >> 3, h = gw & 7;
  const f32x4 zero = {0.f, 0.f, 0.f, 0.f};

  // ---- S = K.Q^T ----
  f32x4 s[4][4];
  {
    const long qkb = (long)win * 49 * 256 + h * 32 + lg * 8;
    bf16x8 ak[4], bq[4];
    #pragma unroll
    for (int mi = 0; mi < 4; ++mi)
      ak[mi] = *(const bf16x8*)(kws + qkb + (mi * 16 + l15) * 256);
    #pragma unroll
    for (int ni = 0; ni < 4; ++ni)
      bq[ni] = *(const bf16x8*)(qws + qkb + (ni * 16 + l15) * 256);
    #pragma unroll
    for (int mi = 0; mi < 4; ++mi)
      #pragma unroll
      for (int ni = 0; ni < 4; ++ni)
        s[mi][ni] = MFMA(ak[mi], bq[ni], zero);
  }

  // ---- softmax over tk per tq-column ----
  const float scale = 0.17677669529663687f;
  #pragma unroll
  for (int ni = 0; ni < 4; ++ni) {
    int tq = ni * 16 + l15;
    int tqc = tq < 49 ? tq : 48;
    #pragma unroll
    for (int mi = 0; mi < 4; ++mi)
      #pragma unroll
      for (int r = 0; r < 4; ++r) {
        int tk = mi * 16 + lg * 4 + r;
        float v = s[mi][ni][r];
        s[mi][ni][r] = (tk < 49) ? (v * scale + bias[tqc * 49 + tk]) : -1e30f;
      }
    float m = -1e30f;
    #pragma unroll
    for (int mi = 0; mi < 4; ++mi)
      #pragma unroll
      for (int r = 0; r < 4; ++r) m = fmaxf(m, s[mi][ni][r]);
    m = fmaxf(m, __shfl_xor(m, 16));
    m = fmaxf(m, __shfl_xor(m, 32));
    float sum = 0.f;
    #pragma unroll
    for (int mi = 0; mi < 4; ++mi)
      #pragma unroll
      for (int r = 0; r < 4; ++r) {
        float e = __expf(s[mi][ni][r] - m);
        s[mi][ni][r] = e;
        sum += e;
      }
    sum += __shfl_xor(sum, 16);
    sum += __shfl_xor(sum, 32);
    float inv = 1.0f / sum;
    #pragma unroll
    for (int mi = 0; mi < 4; ++mi)
      #pragma unroll
      for (int r = 0; r < 4; ++r) s[mi][ni][r] *= inv;
  }

  // ---- P -> wave-private LDS (bf16, swizzled, 49 rows) ----
  char* pw = lds + w * PSTRIDE;
  #pragma unroll
  for (int ni = 0; ni < 4; ++ni) {
    int tq = ni * 16 + l15;
    if (tq < 49) {
      #pragma unroll
      for (int mi = 0; mi < 4; ++mi) {
        int tk0 = mi * 16 + lg * 4;
        uint2 v = {pk2(s[mi][ni][0], s[mi][ni][1]),
                   pk2(s[mi][ni][2], s[mi][ni][3])};
        *(uint2*)(pw + tq * 128 + ((tk0 * 2) ^ ((tq & 7) << 4))) = v;
      }
    }
  }

  // ---- attn out: coalesced stream (overlaps PV) ----
  {
    float* abase = attn_out + ((long)win * 8 + h) * 2401;
    #pragma unroll
    for (int it = 0; it < 38; ++it) {
      int f = it * 64 + lane;
      if (f < 2401) {
        int tq = f / 49, tk = f - tq * 49;
        unsigned short pv =
            *(const unsigned short*)(pw + tq * 128 + ((tk * 2) ^ ((tq & 7) << 4)));
        abase[f] = b2f(pv);
      }
    }
  }

  // ---- O = Vt.P^T -> o_ws[win][h][49][32] bf16 ----
  {
    f32x4 o[2][4];
    #pragma unroll
    for (int i = 0; i < 2; ++i)
      #pragma unroll
      for (int j = 0; j < 4; ++j) o[i][j] = zero;
    #pragma unroll
    for (int ks = 0; ks < 2; ++ks) {
      const int tkc = ks * 32 + lg * 8;
      bf16x8 av[2], bp[4];
      #pragma unroll
      for (int mi = 0; mi < 2; ++mi) {
        int e = h * 32 + mi * 16 + l15;
        av[mi] = *(const bf16x8*)(vt + ((long)win * 256 + e) * 64 + tkc);
      }
      #pragma unroll
      for (int ni = 0; ni < 4; ++ni) {
        int tq = ni * 16 + l15;
        int tqc = tq < 49 ? tq : 48;
        bp[ni] = *(const bf16x8*)(pw + tqc * 128 + ((tkc * 2) ^ ((tqc & 7) << 4)));
      }
      #pragma unroll
      for (int mi = 0; mi < 2; ++mi)
        #pragma unroll
        for (int ni = 0; ni < 4; ++ni)
          o[mi][ni] = MFMA(av[mi], bp[ni], o[mi][ni]);
    }
    unsigned short* ob = o_ws + ((long)win * 8 + h) * 49 * 32;
    #pragma unroll
    for (int mi = 0; mi < 2; ++mi)
      #pragma unroll
      for (int ni = 0; ni < 4; ++ni) {
        int tq = ni * 16 + l15;
        if (tq < 49) {
          int el0 = mi * 16 + lg * 4;
          uint2 v = {pk2(o[mi][ni][0], o[mi][ni][1]),
                     pk2(o[mi][ni][2], o[mi][ni][3])};
          *(uint2*)(ob + tq * 32 + el0) = v;
        }
      }
  }
}

// ================= K3: output projection =================
__global__ __launch_bounds__(256, 4) void out_proj(
    const unsigned short* __restrict__ o_ws, const unsigned short* __restrict__ wo,
    const float* __restrict__ bo, float* __restrict__ out)
{
  __shared__ __align__(16) float obuf[49 * 196];
  const int tid = threadIdx.x;
  const int w = tid >> 6, lane = tid & 63;
  const int l15 = lane & 15, lg = lane >> 4;
  const int win = blockIdx.x;
  const int bi = win >> 6, w1 = (win >> 3) & 7, w2 = win & 7;
  const f32x4 zero = {0.f, 0.f, 0.f, 0.f};

  f32x4 acc[3][4];
  #pragma unroll
  for (int j = 0; j < 3; ++j)
    #pragma unroll
    for (int tt = 0; tt < 4; ++tt) acc[j][tt] = zero;

  #pragma unroll
  for (int ks = 0; ks < 8; ++ks) {
    const int ec = ks * 32 + lg * 8;
    bf16x8 aW[3], bO[4];
    #pragma unroll
    for (int j = 0; j < 3; ++j)
      aW[j] = *(const bf16x8*)(wo + ((w * 3 + j) * 16 + l15) * 256 + ec);
    #pragma unroll
    for (int tt = 0; tt < 4; ++tt) {
      int t = tt * 16 + l15;
      int tc = t < 49 ? t : 48;
      bO[tt] = *(const bf16x8*)(o_ws + ((long)(win * 8 + ks) * 49 + tc) * 32 + lg * 8);
    }
    #pragma unroll
    for (int j = 0; j < 3; ++j)
      #pragma unroll
      for (int tt = 0; tt < 4; ++tt)
        acc[j][tt] = MFMA(aW[j], bO[tt], acc[j][tt]);
  }
  #pragma unroll
  for (int j = 0; j < 3; ++j)
    #pragma unroll
    for (int tt = 0; tt < 4; ++tt) {
      int t = tt * 16 + l15;
      if (t < 49) {
        int oc0 = (w * 3 + j) * 16 + lg * 4;
        *(f32x4*)(obuf + t * 196 + oc0) = acc[j][tt];
      }
    }
  __syncthreads();

  const long obase = (long)bi * 602112 + (w1 * 7) * 56 + w2 * 7;
  for (int idx = tid; idx < 192 * 49; idx += 256) {
    int oc = idx / 49, t = idx - oc * 49;
    out[obase + oc * 3136 + (t / 7) * 56 + (t % 7)] = obuf[t * 196 + oc] + bo[oc];
  }
}

extern "C" void kernel_launch(void* const* d_in, const int* in_sizes, int n_in,
                              void* d_out, int out_size, void* d_ws, size_t ws_size,
                              hipStream_t stream)
{
  const float* x    = (const float*)d_in[0];
  const float* mask = (const float*)d_in[1];
  const float* Wq   = (const float*)d_in[2];
  const float* Wkv  = (const float*)d_in[3];
  const float* Wo   = (const float*)d_in[4];
  const float* bo   = (const float*)d_in[5];
  const float* pos  = (const float*)d_in[6];

  float* out  = (float*)d_out;
  float* attn = out + OUT0;

  char* ws = (char*)d_ws;
  unsigned short* o_ws = (unsigned short*)ws;
  unsigned short* qws  = (unsigned short*)(ws + Q_OFF);
  unsigned short* kws  = (unsigned short*)(ws + K_OFF);
  unsigned short* vt   = (unsigned short*)(ws + V_OFF);
  unsigned short* wqkv = (unsigned short*)(ws + WQKV_OFF);
  unsigned short* wo   = (unsigned short*)(ws + WO_OFF);
  float*          bias = (float*)(ws + BIAS_OFF);

  prep<<<778, 256, 0, stream>>>(mask, Wq, Wkv, Wo, pos, wqkv, wo, bias);
  qkvv_gemm<<<NWIN, 256, 0, stream>>>(x, wqkv, qws, kws, vt);
  attn_core<<<4096, 256, 0, stream>>>(qws, kws, vt, bias, attn, o_ws);
  out_proj<<<NWIN, 256, 0, stream>>>(o_ws, wo, bo, out);
}

// Round 10
// 319.961 us; speedup vs baseline: 1.1174x; 1.1174x over previous
//
#include <hip/hip_runtime.h>

// LocalAttention P=7 window attention — split-pipeline bf16 MFMA.
// Round 10: qkvv ran exactly at achieved-BW (454MB @ 2.5TB/s = 180us); the
// x window-gather (28B runs, 2.3x line over-fetch) and window-regrouped
// stores were the cost. Front-end is now a PURE streaming GEMM over image
// layout: Q,K,V stored [bi][s][e] (s=row*56+col; 3136=49*64, no tails).
// Window mapping moves into attn_core addressing (srow(t)); V transposed
// per-wave in LDS (4.6KB). out_proj / o_ws / prep unchanged.

#define NWIN 2048
#define OUT0 19267584L

typedef __attribute__((ext_vector_type(8))) short bf16x8;
typedef __attribute__((ext_vector_type(4))) float f32x4;

#define MFMA(a, b, c) __builtin_amdgcn_mfma_f32_16x16x32_bf16(a, b, c, 0, 0, 0)

__device__ __forceinline__ unsigned short f2b(float f) {
  unsigned u = __builtin_bit_cast(unsigned, f);
  return (unsigned short)((u + 0x7FFFu + ((u >> 16) & 1u)) >> 16);
}
__device__ __forceinline__ unsigned pk2(float a, float b) {
  return (unsigned)f2b(a) | ((unsigned)f2b(b) << 16);
}
__device__ __forceinline__ float b2f(unsigned short h) {
  unsigned u = ((unsigned)h) << 16;
  return __builtin_bit_cast(float, u);
}

// ---- workspace layout ----
// o_ws 51,380,224 ; q/k/v each 32*3136*256*2 = 51,380,224 ; weights ; bias
#define OWS_BYTES  (2048L * 8 * 49 * 32 * 2)
#define QKV_BYTES  (32L * 3136 * 256 * 2)
#define Q_OFF      OWS_BYTES
#define K_OFF      (Q_OFF + QKV_BYTES)
#define V_OFF      (K_OFF + QKV_BYTES)
#define WQKV_OFF   (V_OFF + QKV_BYTES)
#define WO_OFF     (WQKV_OFF + 768L * 192 * 2)
#define BIAS_OFF   (WO_OFF + 192L * 256 * 2)

// ================= K0: weight cvt + bias table (tiny) =================
__global__ __launch_bounds__(256) void prep(
    const float* __restrict__ mask, const float* __restrict__ Wq,
    const float* __restrict__ Wkv, const float* __restrict__ Wo,
    const float* __restrict__ pos,
    unsigned short* __restrict__ wqkv, unsigned short* __restrict__ wo,
    float* __restrict__ bias)
{
  int gid = blockIdx.x * 256 + threadIdx.x;
  if (gid < 147456)       wqkv[gid] = f2b(gid < 49152 ? Wq[gid] : Wkv[gid - 49152]);
  else if (gid < 196608)  { int i = gid - 147456; wo[i] = f2b(Wo[i]); }
  else if (gid < 199009)  {
    int i = gid - 196608;
    int tq = i / 49, tk = i - tq * 49;
    int r0 = tk / 7 - tq / 7 + 6, r1 = tk % 7 - tq % 7 + 6;
    bias[i] = mask[i] + pos[r0 * 13 + r1];
  }
}

// ================= K1: pure streaming QKV GEMM =================
// Block = (bi, s-tile of 64). Stage x[c][s0..s0+63] (256B contiguous rows)
// -> LDS xs[64 s][200 c] bf16. 4 waves x 3 e-tiles each cover e=0..767.
// All tiles one orientation: D[e][s], stores [s][e] rows (128B runs).
__global__ __launch_bounds__(256, 4) void qkv_gemm(
    const float* __restrict__ x, const unsigned short* __restrict__ wqkv,
    unsigned short* __restrict__ qws, unsigned short* __restrict__ kws,
    unsigned short* __restrict__ vws)
{
  __shared__ __align__(16) unsigned short xs[64 * 200];  // 25600 B
  const int tid = threadIdx.x;
  const int w = tid >> 6, lane = tid & 63;
  const int l15 = lane & 15, lg = lane >> 4;
  const int bi = blockIdx.x / 49;
  const int s0 = (blockIdx.x - bi * 49) * 64;
  const f32x4 zero = {0.f, 0.f, 0.f, 0.f};

  // ---- stage: coalesced f32 reads, transposed bf16 LDS writes ----
  {
    const float* xb = x + (long)bi * 192 * 3136 + s0;
    #pragma unroll
    for (int r = 0; r < 12; ++r) {
      int fid = r * 256 + tid;        // 3072 float4 chunks: 192c x 16
      int c = fid >> 4, q4 = fid & 15;
      float4 vv = *(const float4*)(xb + c * 3136 + q4 * 4);
      xs[(q4 * 4 + 0) * 200 + c] = f2b(vv.x);
      xs[(q4 * 4 + 1) * 200 + c] = f2b(vv.y);
      xs[(q4 * 4 + 2) * 200 + c] = f2b(vv.z);
      xs[(q4 * 4 + 3) * 200 + c] = f2b(vv.w);
    }
  }
  __syncthreads();

  #pragma unroll
  for (int i = 0; i < 3; ++i) {
    const int ti = i * 4 + w;          // 0..11 -> e 0..767
    const int e_base = ti * 64;
    f32x4 acc[4][4];
    #pragma unroll
    for (int a = 0; a < 4; ++a)
      #pragma unroll
      for (int b = 0; b < 4; ++b) acc[a][b] = zero;

    #pragma unroll
    for (int ks = 0; ks < 6; ++ks) {
      const int kc = ks * 32 + lg * 8;
      bf16x8 a[4], b[4];
      #pragma unroll
      for (int mi = 0; mi < 4; ++mi)
        a[mi] = *(const bf16x8*)(wqkv + (e_base + mi * 16 + l15) * 192 + kc);
      #pragma unroll
      for (int ni = 0; ni < 4; ++ni)
        b[ni] = *(const bf16x8*)(xs + (ni * 16 + l15) * 200 + kc);
      #pragma unroll
      for (int mi = 0; mi < 4; ++mi)
        #pragma unroll
        for (int ni = 0; ni < 4; ++ni)
          acc[mi][ni] = MFMA(a[mi], b[ni], acc[mi][ni]);
    }
    unsigned short* dst = (ti < 4) ? qws : (ti < 8) ? kws : vws;
    const int eb = e_base & 255;
    #pragma unroll
    for (int ni = 0; ni < 4; ++ni) {
      long srow = (long)bi * 3136 + s0 + ni * 16 + l15;   // always valid
      #pragma unroll
      for (int mi = 0; mi < 4; ++mi) {
        int e0 = eb + mi * 16 + lg * 4;
        uint2 v = {pk2(acc[mi][ni][0], acc[mi][ni][1]),
                   pk2(acc[mi][ni][2], acc[mi][ni][3])};
        *(uint2*)(dst + srow * 256 + e0) = v;
      }
    }
  }
}

// ================= K2: attention core (1 wave = 1 (win,head)) =================
// LDS per wave: P [49+][64] swz (6272B) + Vt [32 e][72 t] (4608B). No barriers.
#define PSTRIDE 6272
#define VT_OFF  (4 * PSTRIDE)          // 25088
#define VTSTRIDE 4608                  // 32*72*2
#define LDS_TOT (VT_OFF + 4 * VTSTRIDE)

__global__ __launch_bounds__(256, 4) void attn_core(
    const unsigned short* __restrict__ qws, const unsigned short* __restrict__ kws,
    const unsigned short* __restrict__ vws, const float* __restrict__ bias,
    float* __restrict__ attn_out, unsigned short* __restrict__ o_ws)
{
  __shared__ __align__(16) char lds[LDS_TOT];
  const int tid = threadIdx.x;
  const int w = tid >> 6, lane = tid & 63;
  const int l15 = lane & 15, lg = lane >> 4;
  const int gw = blockIdx.x * 4 + w;
  const int win = gw >> 3, h = gw & 7;
  const int bi = win >> 6, w1 = (win >> 3) & 7, w2 = win & 7;
  const int sw = (w1 * 7) * 56 + w2 * 7;         // window origin (spatial)
  const long rowbase = (long)bi * 3136;
  const f32x4 zero = {0.f, 0.f, 0.f, 0.f};

  // ---- stage V slice [win rows][h*32..h*32+31] -> Vt_lds[e][t] (transposed) ----
  unsigned short* vt = (unsigned short*)(lds + VT_OFF + w * VTSTRIDE);
  {
    #pragma unroll
    for (int pass = 0; pass < 4; ++pass) {
      int t = pass * 16 + (lane >> 2);
      int tc = t < 49 ? t : 48;
      int e8 = (lane & 3) * 8;
      int srow = sw + (tc / 7) * 56 + (tc % 7);
      bf16x8 vv = *(const bf16x8*)(vws + (rowbase + srow) * 256 + h * 32 + e8);
      #pragma unroll
      for (int j = 0; j < 8; ++j) vt[(e8 + j) * 72 + t] = vv[j];
    }
  }

  // ---- S = K.Q^T (frag rows via window addressing) ----
  f32x4 s[4][4];
  {
    const int dc = h * 32 + lg * 8;
    bf16x8 ak[4], bq[4];
    #pragma unroll
    for (int mi = 0; mi < 4; ++mi) {
      int t = mi * 16 + l15; if (t > 48) t = 48;
      int srow = sw + (t / 7) * 56 + (t % 7);
      ak[mi] = *(const bf16x8*)(kws + (rowbase + srow) * 256 + dc);
    }
    #pragma unroll
    for (int ni = 0; ni < 4; ++ni) {
      int t = ni * 16 + l15; if (t > 48) t = 48;
      int srow = sw + (t / 7) * 56 + (t % 7);
      bq[ni] = *(const bf16x8*)(qws + (rowbase + srow) * 256 + dc);
    }
    #pragma unroll
    for (int mi = 0; mi < 4; ++mi)
      #pragma unroll
      for (int ni = 0; ni < 4; ++ni)
        s[mi][ni] = MFMA(ak[mi], bq[ni], zero);
  }

  // ---- softmax over tk per tq-column ----
  const float scale = 0.17677669529663687f;
  #pragma unroll
  for (int ni = 0; ni < 4; ++ni) {
    int tq = ni * 16 + l15;
    int tqc = tq < 49 ? tq : 48;
    #pragma unroll
    for (int mi = 0; mi < 4; ++mi)
      #pragma unroll
      for (int r = 0; r < 4; ++r) {
        int tk = mi * 16 + lg * 4 + r;
        float v = s[mi][ni][r];
        s[mi][ni][r] = (tk < 49) ? (v * scale + bias[tqc * 49 + tk]) : -1e30f;
      }
    float m = -1e30f;
    #pragma unroll
    for (int mi = 0; mi < 4; ++mi)
      #pragma unroll
      for (int r = 0; r < 4; ++r) m = fmaxf(m, s[mi][ni][r]);
    m = fmaxf(m, __shfl_xor(m, 16));
    m = fmaxf(m, __shfl_xor(m, 32));
    float sum = 0.f;
    #pragma unroll
    for (int mi = 0; mi < 4; ++mi)
      #pragma unroll
      for (int r = 0; r < 4; ++r) {
        float e = __expf(s[mi][ni][r] - m);
        s[mi][ni][r] = e;
        sum += e;
      }
    sum += __shfl_xor(sum, 16);
    sum += __shfl_xor(sum, 32);
    float inv = 1.0f / sum;
    #pragma unroll
    for (int mi = 0; mi < 4; ++mi)
      #pragma unroll
      for (int r = 0; r < 4; ++r) s[mi][ni][r] *= inv;
  }

  // ---- P -> wave-private LDS (bf16, swizzled, 49 rows) ----
  char* pw = lds + w * PSTRIDE;
  #pragma unroll
  for (int ni = 0; ni < 4; ++ni) {
    int tq = ni * 16 + l15;
    if (tq < 49) {
      #pragma unroll
      for (int mi = 0; mi < 4; ++mi) {
        int tk0 = mi * 16 + lg * 4;
        uint2 v = {pk2(s[mi][ni][0], s[mi][ni][1]),
                   pk2(s[mi][ni][2], s[mi][ni][3])};
        *(uint2*)(pw + tq * 128 + ((tk0 * 2) ^ ((tq & 7) << 4))) = v;
      }
    }
  }

  // ---- attn out: coalesced stream (overlaps PV) ----
  {
    float* abase = attn_out + ((long)win * 8 + h) * 2401;
    #pragma unroll
    for (int it = 0; it < 38; ++it) {
      int f = it * 64 + lane;
      if (f < 2401) {
        int tq = f / 49, tk = f - tq * 49;
        unsigned short pv =
            *(const unsigned short*)(pw + tq * 128 + ((tk * 2) ^ ((tq & 7) << 4)));
        abase[f] = b2f(pv);
      }
    }
  }

  // ---- O = Vt.P^T (Vt from LDS) -> o_ws[win][h][49][32] bf16 ----
  {
    f32x4 o[2][4];
    #pragma unroll
    for (int i = 0; i < 2; ++i)
      #pragma unroll
      for (int j = 0; j < 4; ++j) o[i][j] = zero;
    #pragma unroll
    for (int ks = 0; ks < 2; ++ks) {
      const int tkc = ks * 32 + lg * 8;
      bf16x8 av[2], bp[4];
      #pragma unroll
      for (int mi = 0; mi < 2; ++mi) {
        int e = mi * 16 + l15;
        av[mi] = *(const bf16x8*)(vt + e * 72 + tkc);
      }
      #pragma unroll
      for (int ni = 0; ni < 4; ++ni) {
        int tq = ni * 16 + l15;
        int tqc = tq < 49 ? tq : 48;
        bp[ni] = *(const bf16x8*)(pw + tqc * 128 + ((tkc * 2) ^ ((tqc & 7) << 4)));
      }
      #pragma unroll
      for (int mi = 0; mi < 2; ++mi)
        #pragma unroll
        for (int ni = 0; ni < 4; ++ni)
          o[mi][ni] = MFMA(av[mi], bp[ni], o[mi][ni]);
    }
    unsigned short* ob = o_ws + ((long)win * 8 + h) * 49 * 32;
    #pragma unroll
    for (int mi = 0; mi < 2; ++mi)
      #pragma unroll
      for (int ni = 0; ni < 4; ++ni) {
        int tq = ni * 16 + l15;
        if (tq < 49) {
          int el0 = mi * 16 + lg * 4;
          uint2 v = {pk2(o[mi][ni][0], o[mi][ni][1]),
                     pk2(o[mi][ni][2], o[mi][ni][3])};
          *(uint2*)(ob + tq * 32 + el0) = v;
        }
      }
  }
}

// ================= K3: output projection (unchanged) =================
__global__ __launch_bounds__(256, 4) void out_proj(
    const unsigned short* __restrict__ o_ws, const unsigned short* __restrict__ wo,
    const float* __restrict__ bo, float* __restrict__ out)
{
  __shared__ __align__(16) float obuf[49 * 196];
  const int tid = threadIdx.x;
  const int w = tid >> 6, lane = tid & 63;
  const int l15 = lane & 15, lg = lane >> 4;
  const int win = blockIdx.x;
  const int bi = win >> 6, w1 = (win >> 3) & 7, w2 = win & 7;
  const f32x4 zero = {0.f, 0.f, 0.f, 0.f};

  f32x4 acc[3][4];
  #pragma unroll
  for (int j = 0; j < 3; ++j)
    #pragma unroll
    for (int tt = 0; tt < 4; ++tt) acc[j][tt] = zero;

  #pragma unroll
  for (int ks = 0; ks < 8; ++ks) {
    const int ec = ks * 32 + lg * 8;
    bf16x8 aW[3], bO[4];
    #pragma unroll
    for (int j = 0; j < 3; ++j)
      aW[j] = *(const bf16x8*)(wo + ((w * 3 + j) * 16 + l15) * 256 + ec);
    #pragma unroll
    for (int tt = 0; tt < 4; ++tt) {
      int t = tt * 16 + l15;
      int tc = t < 49 ? t : 48;
      bO[tt] = *(const bf16x8*)(o_ws + ((long)(win * 8 + ks) * 49 + tc) * 32 + lg * 8);
    }
    #pragma unroll
    for (int j = 0; j < 3; ++j)
      #pragma unroll
      for (int tt = 0; tt < 4; ++tt)
        acc[j][tt] = MFMA(aW[j], bO[tt], acc[j][tt]);
  }
  #pragma unroll
  for (int j = 0; j < 3; ++j)
    #pragma unroll
    for (int tt = 0; tt < 4; ++tt) {
      int t = tt * 16 + l15;
      if (t < 49) {
        int oc0 = (w * 3 + j) * 16 + lg * 4;
        *(f32x4*)(obuf + t * 196 + oc0) = acc[j][tt];
      }
    }
  __syncthreads();

  const long obase = (long)bi * 602112 + (w1 * 7) * 56 + w2 * 7;
  for (int idx = tid; idx < 192 * 49; idx += 256) {
    int oc = idx / 49, t = idx - oc * 49;
    out[obase + oc * 3136 + (t / 7) * 56 + (t % 7)] = obuf[t * 196 + oc] + bo[oc];
  }
}

extern "C" void kernel_launch(void* const* d_in, const int* in_sizes, int n_in,
                              void* d_out, int out_size, void* d_ws, size_t ws_size,
                              hipStream_t stream)
{
  const float* x    = (const float*)d_in[0];
  const float* mask = (const float*)d_in[1];
  const float* Wq   = (const float*)d_in[2];
  const float* Wkv  = (const float*)d_in[3];
  const float* Wo   = (const float*)d_in[4];
  const float* bo   = (const float*)d_in[5];
  const float* pos  = (const float*)d_in[6];

  float* out  = (float*)d_out;
  float* attn = out + OUT0;

  char* ws = (char*)d_ws;
  unsigned short* o_ws = (unsigned short*)ws;
  unsigned short* qws  = (unsigned short*)(ws + Q_OFF);
  unsigned short* kws  = (unsigned short*)(ws + K_OFF);
  unsigned short* vws  = (unsigned short*)(ws + V_OFF);
  unsigned short* wqkv = (unsigned short*)(ws + WQKV_OFF);
  unsigned short* wo   = (unsigned short*)(ws + WO_OFF);
  float*          bias = (float*)(ws + BIAS_OFF);

  prep<<<778, 256, 0, stream>>>(mask, Wq, Wkv, Wo, pos, wqkv, wo, bias);
  qkv_gemm<<<32 * 49, 256, 0, stream>>>(x, wqkv, qws, kws, vws);
  attn_core<<<4096, 256, 0, stream>>>(qws, kws, vws, bias, attn, o_ws);
  out_proj<<<NWIN, 256, 0, stream>>>(o_ws, wo, bo, out);
}